// Round 9
// baseline (983.889 us; speedup 1.0000x reference)
//
#include <hip/hip_runtime.h>
#include <math.h>

#define NS   64
#define NOBS 10000
#define NB   256
#define TMAX 2048

// workspace layout (floats)
#define PIP_OFF 0
#define ASW_OFF 64                    // swizzled A_prob, 4096 floats
#define LSE_OFF (64 + 4096)
#define ET_OFF  (64 + 4096 + 64)

__device__ __forceinline__ float wsum64(float v) {
  v += __shfl_xor(v, 1);
  v += __shfl_xor(v, 2);
  v += __shfl_xor(v, 4);
  v += __shfl_xor(v, 8);
  v += __shfl_xor(v, 16);
  v += __shfl_xor(v, 32);
  return v;
}

// DPP row_ror:N within 16-lane rows. Direction probed at prep time.
#define DPPROR(S, N)                                                           \
  __int_as_float(__builtin_amdgcn_update_dpp(                                  \
      0, __float_as_int(S), 0x120 + (N), 0xF, 0xF, true))

// full xor-32 + xor-16 lane sum via gfx950 permlane swaps (parity-agnostic).
#define COMB(Q) ({                                                             \
    float a32_ = (Q); float b32_;                                              \
    asm("v_mov_b32 %0, %1" : "=v"(b32_) : "v"(a32_));                          \
    asm("v_permlane32_swap_b32 %0, %1" : "+v"(a32_), "+v"(b32_));              \
    float s32_ = a32_ + b32_;                                                  \
    float a16_ = s32_; float b16_;                                             \
    asm("v_mov_b32 %0, %1" : "=v"(b16_) : "v"(s32_));                          \
    asm("v_permlane16_swap_b32 %0, %1" : "+v"(a16_), "+v"(b16_));              \
    a16_ + b16_; })

// ---------------- precompute: softmax(pi), column-softmax(A), swizzle ------
__global__ __launch_bounds__(64) void prep_small(const float* __restrict__ pi,
                                                 const float* __restrict__ A,
                                                 float* __restrict__ ws) {
  const int l = threadIdx.x;  // 0..63
  const int r = l & 15, c = l >> 4;
  float p = pi[l];
  float m = p;
  m = fmaxf(m, __shfl_xor(m, 1));
  m = fmaxf(m, __shfl_xor(m, 2));
  m = fmaxf(m, __shfl_xor(m, 4));
  m = fmaxf(m, __shfl_xor(m, 8));
  m = fmaxf(m, __shfl_xor(m, 16));
  m = fmaxf(m, __shfl_xor(m, 32));
  float ex = expf(p - m);
  float s = wsum64(ex);
  ws[PIP_OFF + l] = ex / s;

  __shared__ float Ap[NS * NS];
  float cm = -3.0e38f;
  for (int i = 0; i < NS; ++i) cm = fmaxf(cm, A[i * NS + l]);
  float cs = 0.f;
  for (int i = 0; i < NS; ++i) cs += expf(A[i * NS + l] - cm);
  float inv = 1.0f / cs;
  for (int i = 0; i < NS; ++i) Ap[i * NS + l] = expf(A[i * NS + l] - cm) * inv;
  __syncthreads();

  // probe the hardware's row_ror direction: does lane l receive (l-1)&15 ?
  const int probe = __builtin_amdgcn_update_dpp(0, l, 0x121, 0xF, 0xF, true);
  const int dir = ((probe & 15) == ((r - 1) & 15)) ? 1 : -1;  // uniform

  // systolic swizzle matched to measured direction:
  // lane l=(r,c): aw[g][j] = Ap[r+16g][16c + ((r - dir*j)&15)]
  for (int g = 0; g < 4; ++g)
    for (int j = 0; j < 16; ++j)
      ws[ASW_OFF + l * 64 + g * 16 + j] =
          Ap[(r + 16 * g) * NS + (16 * c + ((r - dir * j) & 15))];
}

// ---------------- precompute: per-state emission logsumexp ----------------
__global__ __launch_bounds__(256) void emis_lse(const float* __restrict__ E,
                                                float* __restrict__ ws) {
  const int s = blockIdx.x;  // state
  const float* row = E + (size_t)s * NOBS;
  __shared__ float red[4];
  float m = -3.0e38f;
  for (int o = threadIdx.x; o < NOBS; o += 256) m = fmaxf(m, row[o]);
  m = fmaxf(m, __shfl_xor(m, 1));
  m = fmaxf(m, __shfl_xor(m, 2));
  m = fmaxf(m, __shfl_xor(m, 4));
  m = fmaxf(m, __shfl_xor(m, 8));
  m = fmaxf(m, __shfl_xor(m, 16));
  m = fmaxf(m, __shfl_xor(m, 32));
  const int wid = threadIdx.x >> 6;
  if ((threadIdx.x & 63) == 0) red[wid] = m;
  __syncthreads();
  m = fmaxf(fmaxf(red[0], red[1]), fmaxf(red[2], red[3]));
  __syncthreads();
  float sum = 0.f;
  for (int o = threadIdx.x; o < NOBS; o += 256) sum += expf(row[o] - m);
  sum = wsum64(sum);
  if ((threadIdx.x & 63) == 0) red[wid] = sum;
  __syncthreads();
  if (threadIdx.x == 0)
    ws[LSE_OFF + s] = m + logf(red[0] + red[1] + red[2] + red[3]);
}

// ---------------- precompute: EprobT[obs*64 + s] = exp(E[s,obs] - lse[s]) ----
__global__ __launch_bounds__(256) void emis_fill(const float* __restrict__ E,
                                                 float* __restrict__ ws) {
  const int idx = blockIdx.x * 256 + threadIdx.x;  // = obs*64 + s
  if (idx >= NS * NOBS) return;
  const int s = idx & 63;
  const int obs = idx >> 6;
  ws[ET_OFF + idx] = expf(E[(size_t)s * NOBS + obs] - ws[LSE_OFF + s]);
}

// ---------------- forward recursion: 2 batches per wave ----------------
// Two independent recurrences (batches b and b+128) interleaved in one wave:
// fills single-wave latency bubbles with the other batch's instructions.
// Per STEP2 (one time step, both batches): 2 asm ds_read (t+2 prefetch, 4-slot
// static rotation, exact lgkmcnt(4)); 30 DPP rotations; 128 scalar fmas
// (8 independent chains, depth 16); 8 permlane-butterfly combines; selects.
// Emissions staged per 64-step chunk via global_load_lds (one vmcnt(0)/chunk).
// ebuf row layout: row = half*128 + bat*64 + (t&63); addr bit-trick:
// row(t,bat) = ((t&64)<<1) | (bat<<6) | (t&63).

#define PIN8(i)                                                                \
  asm volatile("" : "+v"(aw[(i)]), "+v"(aw[(i) + 1]), "+v"(aw[(i) + 2]),       \
                    "+v"(aw[(i) + 3]), "+v"(aw[(i) + 4]), "+v"(aw[(i) + 5]),   \
                    "+v"(aw[(i) + 6]), "+v"(aw[(i) + 7]))
#define PIN_AW() do { PIN8(0); PIN8(8); PIN8(16); PIN8(24);                    \
                      PIN8(32); PIN8(40); PIN8(48); PIN8(56); } while (0)

// stage chunk (64 steps) for both batches into half HALF of ebuf
#define STAGE2(XS0, XS1, HALF) do {                                            \
    _Pragma("unroll")                                                          \
    for (int k_ = 0; k_ < 64; ++k_) {                                          \
      const int x0_ = __builtin_amdgcn_readlane((XS0), k_);                    \
      __builtin_amdgcn_global_load_lds(                                        \
          ET + ((size_t)(unsigned)x0_ << 6) + lane,                            \
          &ebuf[((((HALF) << 1) + 0) * 64 + k_) * 64], 4, 0, 0);               \
      const int x1_ = __builtin_amdgcn_readlane((XS1), k_);                    \
      __builtin_amdgcn_global_load_lds(                                        \
          ET + ((size_t)(unsigned)x1_ << 6) + lane,                            \
          &ebuf[((((HALF) << 1) + 1) * 64 + k_) * 64], 4, 0, 0);               \
    } } while (0)

#define EREAD(DST, ADDR, IMM)                                                  \
  asm volatile("ds_read_b32 %0, %1 offset:" #IMM : "=v"(DST) : "v"(ADDR))

#define STEP2(u) do {                                                          \
    const int t_ = t0 + (u);                                                   \
    { const int tp_ = t_ + 2;  /* prefetch both batches' e for t+2 */          \
      const unsigned rbi_ = (unsigned)(((tp_ & 64) << 1) + (tp_ & 63));        \
      const unsigned ea_ = ebase + (rbi_ << 8) + ((unsigned)lane << 2);        \
      EREAD(pe0[((u) + 2) & 3], ea_, 0);                                       \
      EREAD(pe1[((u) + 2) & 3], ea_, 16384); }                                 \
    asm volatile("s_waitcnt lgkmcnt(4)");                                      \
    __builtin_amdgcn_sched_barrier(0);                                         \
    const float e0_ = pe0[(u)];                                                \
    const float e1_ = pe1[(u)];                                                \
    float es0_, es1_;                                                          \
    if (((u) & 1) != 0) {  /* exact pow-2 rescale every 2 steps, per batch */  \
      const unsigned r0_ = __builtin_amdgcn_readfirstlane(__float_as_uint(s0));\
      const int se0_ = (int)((r0_ >> 23) & 0xFFu) - 127;                       \
      es0_ = e0_ * __uint_as_float((unsigned)(127 - se0_) << 23);              \
      E2a += se0_;                                                             \
      const unsigned r1_ = __builtin_amdgcn_readfirstlane(__float_as_uint(s1));\
      const int se1_ = (int)((r1_ >> 23) & 0xFFu) - 127;                       \
      es1_ = e1_ * __uint_as_float((unsigned)(127 - se1_) << 23);              \
      E2b += se1_;                                                             \
    } else { es0_ = e0_; es1_ = e1_; }                                         \
    float ra_[16], rx_[16];                                                    \
    ra_[0] = s0;             rx_[0] = s1;                                      \
    ra_[1] = DPPROR(s0, 1);  rx_[1] = DPPROR(s1, 1);                           \
    ra_[2] = DPPROR(s0, 2);  rx_[2] = DPPROR(s1, 2);                           \
    ra_[3] = DPPROR(s0, 3);  rx_[3] = DPPROR(s1, 3);                           \
    ra_[4] = DPPROR(s0, 4);  rx_[4] = DPPROR(s1, 4);                           \
    ra_[5] = DPPROR(s0, 5);  rx_[5] = DPPROR(s1, 5);                           \
    ra_[6] = DPPROR(s0, 6);  rx_[6] = DPPROR(s1, 6);                           \
    ra_[7] = DPPROR(s0, 7);  rx_[7] = DPPROR(s1, 7);                           \
    ra_[8] = DPPROR(s0, 8);  rx_[8] = DPPROR(s1, 8);                           \
    ra_[9] = DPPROR(s0, 9);  rx_[9] = DPPROR(s1, 9);                           \
    ra_[10] = DPPROR(s0, 10); rx_[10] = DPPROR(s1, 10);                        \
    ra_[11] = DPPROR(s0, 11); rx_[11] = DPPROR(s1, 11);                        \
    ra_[12] = DPPROR(s0, 12); rx_[12] = DPPROR(s1, 12);                        \
    ra_[13] = DPPROR(s0, 13); rx_[13] = DPPROR(s1, 13);                        \
    ra_[14] = DPPROR(s0, 14); rx_[14] = DPPROR(s1, 14);                        \
    ra_[15] = DPPROR(s0, 15); rx_[15] = DPPROR(s1, 15);                        \
    float q0_ = 0.f, q1_ = 0.f, q2_ = 0.f, q3_ = 0.f;                          \
    float p0_ = 0.f, p1_ = 0.f, p2_ = 0.f, p3_ = 0.f;                          \
    _Pragma("unroll")                                                          \
    for (int j_ = 0; j_ < 16; ++j_) {                                          \
      q0_ = fmaf(aw[j_],      ra_[j_], q0_);                                   \
      p0_ = fmaf(aw[j_],      rx_[j_], p0_);                                   \
      q1_ = fmaf(aw[16 + j_], ra_[j_], q1_);                                   \
      p1_ = fmaf(aw[16 + j_], rx_[j_], p1_);                                   \
      q2_ = fmaf(aw[32 + j_], ra_[j_], q2_);                                   \
      p2_ = fmaf(aw[32 + j_], rx_[j_], p2_);                                   \
      q3_ = fmaf(aw[48 + j_], ra_[j_], q3_);                                   \
      p3_ = fmaf(aw[48 + j_], rx_[j_], p3_);                                   \
    }                                                                          \
    const float qt0_ = COMB(q0_);                                              \
    const float pt0_ = COMB(p0_);                                              \
    const float qt1_ = COMB(q1_);                                              \
    const float pt1_ = COMB(p1_);                                              \
    const float qt2_ = COMB(q2_);                                              \
    const float pt2_ = COMB(p2_);                                              \
    const float qt3_ = COMB(q3_);                                              \
    const float pt3_ = COMB(p3_);                                              \
    const float qa_ = (cgrp & 1) ? qt1_ : qt0_;                                \
    const float qb_ = (cgrp & 1) ? qt3_ : qt2_;                                \
    const float qs_ = (cgrp & 2) ? qb_ : qa_;                                  \
    const float pa_ = (cgrp & 1) ? pt1_ : pt0_;                                \
    const float pb_ = (cgrp & 1) ? pt3_ : pt2_;                                \
    const float ps_ = (cgrp & 2) ? pb_ : pa_;                                  \
    const float w0_ = es0_ * ((t_ == 0) ? pip : qs_);                          \
    const float w1_ = es1_ * ((t_ == 0) ? pip : ps_);                          \
    if (t_ == Tn0 - 1) { vs0 = w0_; e2s0 = E2a; }                              \
    if (t_ == Tn1 - 1) { vs1 = w1_; e2s1 = E2b; }                              \
    s0 = w0_;                                                                  \
    s1 = w1_;                                                                  \
  } while (0)

#define GROUP2(T0) do {                                                        \
    const int t0 = (T0);                                                       \
    STEP2(0); STEP2(1); STEP2(2); STEP2(3);                                    \
  } while (0)

__global__ void __attribute__((amdgpu_flat_work_group_size(64, 64)))
__attribute__((amdgpu_waves_per_eu(1, 1)))
hmm_fwd(const int* __restrict__ x, const int* __restrict__ T,
        const float* __restrict__ ws, float* __restrict__ out) {
  const int lane = threadIdx.x;
  const int b0 = blockIdx.x;          // batch pair: b0 and b0+128
  const int cgrp = lane >> 4;
  const float* __restrict__ ET = ws + ET_OFF;
  const int* __restrict__ xb0 = x + (size_t)b0 * TMAX;
  const int* __restrict__ xb1 = x + (size_t)(b0 + NB / 2) * TMAX;
  const int Tn0 = T[b0];
  const int Tn1 = T[b0 + NB / 2];

  __shared__ __align__(16) float ebuf[256 * 64];  // 64 KB: 2 halves x 2 batches
  const unsigned ebase = (unsigned)(size_t)ebuf;  // flat->LDS trunc

  // swizzled A tile for this lane: aw[g*16+j], pinned resident in VGPRs
  float aw[NS];
  {
    const float4* ar = (const float4*)(ws + ASW_OFF + lane * NS);
#pragma unroll
    for (int q = 0; q < 16; ++q) {
      float4 f = ar[q];
      aw[4 * q + 0] = f.x; aw[4 * q + 1] = f.y;
      aw[4 * q + 2] = f.z; aw[4 * q + 3] = f.w;
    }
  }
  PIN_AW();

  const float pip = ws[PIP_OFF + lane];

  // stage chunk 0 (both batches), drain, prime the e rotations for t=0,1
  int xv0 = xb0[lane], xv1 = xb1[lane];
  STAGE2(xv0, xv1, 0);
  int xn0 = xb0[64 + lane], xn1 = xb1[64 + lane];
  asm volatile("s_waitcnt vmcnt(0)" ::: "memory");

  float pe0[4], pe1[4];
  {
    const unsigned ea_ = ebase + ((unsigned)lane << 2);
    EREAD(pe0[0], ea_, 0);    EREAD(pe1[0], ea_, 16384);
    EREAD(pe0[1], ea_, 256);  EREAD(pe1[1], ea_, 16640);
  }

  float s0 = 1.0f, s1 = 1.0f;   // exponent 0 -> se=0 at t=0
  float vs0 = 0.f, vs1 = 0.f;
  int E2a = 0, E2b = 0, e2s0 = 0, e2s1 = 0;

  const int Tmx = (Tn0 > Tn1) ? Tn0 : Tn1;
  const int nch = (Tmx + 63) >> 6;
  for (int c = 0; c < nch; ++c) {
    const int tb = c << 6;
    if (c + 1 < TMAX / 64) STAGE2(xn0, xn1, (c + 1) & 1);
    xn0 = ((c + 2) < TMAX / 64) ? xb0[((c + 2) << 6) + lane] : 0;
    xn1 = ((c + 2) < TMAX / 64) ? xb1[((c + 2) << 6) + lane] : 0;
#pragma unroll 1
    for (int gp = 0; gp < 15; ++gp) {   // t = tb .. tb+59
      GROUP2(tb + (gp << 2));
    }
    // drain staging of chunk c+1 before the last group prefetches across
    asm volatile("s_waitcnt vmcnt(0)" ::: "memory");
    GROUP2(tb + 60);                    // t = tb+60 .. tb+63
  }

  const float sf0 = wsum64(vs0);
  const float sf1 = wsum64(vs1);
  if (lane == 0) {
    out[b0] =
        (float)((double)logf(sf0) + (double)e2s0 * 0.6931471805599453);
    out[b0 + NB / 2] =
        (float)((double)logf(sf1) + (double)e2s1 * 0.6931471805599453);
  }
}

extern "C" void kernel_launch(void* const* d_in, const int* in_sizes, int n_in,
                              void* d_out, int out_size, void* d_ws, size_t ws_size,
                              hipStream_t stream) {
  const int*   x  = (const int*)d_in[0];
  const int*   T  = (const int*)d_in[1];
  const float* pi = (const float*)d_in[2];
  const float* A  = (const float*)d_in[3];
  const float* E  = (const float*)d_in[4];
  float* out = (float*)d_out;
  float* ws  = (float*)d_ws;

  prep_small<<<1, 64, 0, stream>>>(pi, A, ws);
  emis_lse<<<NS, 256, 0, stream>>>(E, ws);
  emis_fill<<<(NS * NOBS + 255) / 256, 256, 0, stream>>>(E, ws);
  hmm_fwd<<<NB / 2, 64, 0, stream>>>(x, T, ws, out);
}

// Round 11
// 456.162 us; speedup vs baseline: 2.1569x; 2.1569x over previous
//
#include <hip/hip_runtime.h>
#include <math.h>

#define NS   64
#define NOBS 10000
#define NB   256
#define TMAX 2048

// workspace layout (floats)
#define PIP_OFF 0
#define ASW_OFF 64                    // swizzled A_prob, 4096 floats
#define LSE_OFF (64 + 4096)
#define ET_OFF  (64 + 4096 + 64)

__device__ __forceinline__ float wsum64(float v) {
  v += __shfl_xor(v, 1);
  v += __shfl_xor(v, 2);
  v += __shfl_xor(v, 4);
  v += __shfl_xor(v, 8);
  v += __shfl_xor(v, 16);
  v += __shfl_xor(v, 32);
  return v;
}

// ---------------- precompute: softmax(pi), column-softmax(A), swizzle ------
__global__ __launch_bounds__(64) void prep_small(const float* __restrict__ pi,
                                                 const float* __restrict__ A,
                                                 float* __restrict__ ws) {
  const int l = threadIdx.x;  // 0..63
  const int r = l & 15, c = l >> 4;
  float p = pi[l];
  float m = p;
  m = fmaxf(m, __shfl_xor(m, 1));
  m = fmaxf(m, __shfl_xor(m, 2));
  m = fmaxf(m, __shfl_xor(m, 4));
  m = fmaxf(m, __shfl_xor(m, 8));
  m = fmaxf(m, __shfl_xor(m, 16));
  m = fmaxf(m, __shfl_xor(m, 32));
  float ex = expf(p - m);
  float s = wsum64(ex);
  ws[PIP_OFF + l] = ex / s;

  __shared__ float Ap[NS * NS];
  float cm = -3.0e38f;
  for (int i = 0; i < NS; ++i) cm = fmaxf(cm, A[i * NS + l]);
  float cs = 0.f;
  for (int i = 0; i < NS; ++i) cs += expf(A[i * NS + l] - cm);
  float inv = 1.0f / cs;
  for (int i = 0; i < NS; ++i) Ap[i * NS + l] = expf(A[i * NS + l] - cm) * inv;
  __syncthreads();

  // probe the hardware's row_ror direction: does lane l receive (l-1)&15 ?
  const int probe = __builtin_amdgcn_update_dpp(0, l, 0x121, 0xF, 0xF, true);
  const int dir = ((probe & 15) == ((r - 1) & 15)) ? 1 : -1;  // uniform

  // systolic swizzle matched to measured direction:
  // lane l=(r,c): aw[g][j] = Ap[r+16g][16c + ((r - dir*j)&15)]
  for (int g = 0; g < 4; ++g)
    for (int j = 0; j < 16; ++j)
      ws[ASW_OFF + l * 64 + g * 16 + j] =
          Ap[(r + 16 * g) * NS + (16 * c + ((r - dir * j) & 15))];
}

// ---------------- precompute: per-state emission logsumexp ----------------
__global__ __launch_bounds__(256) void emis_lse(const float* __restrict__ E,
                                                float* __restrict__ ws) {
  const int s = blockIdx.x;  // state
  const float* row = E + (size_t)s * NOBS;
  __shared__ float red[4];
  float m = -3.0e38f;
  for (int o = threadIdx.x; o < NOBS; o += 256) m = fmaxf(m, row[o]);
  m = fmaxf(m, __shfl_xor(m, 1));
  m = fmaxf(m, __shfl_xor(m, 2));
  m = fmaxf(m, __shfl_xor(m, 4));
  m = fmaxf(m, __shfl_xor(m, 8));
  m = fmaxf(m, __shfl_xor(m, 16));
  m = fmaxf(m, __shfl_xor(m, 32));
  const int wid = threadIdx.x >> 6;
  if ((threadIdx.x & 63) == 0) red[wid] = m;
  __syncthreads();
  m = fmaxf(fmaxf(red[0], red[1]), fmaxf(red[2], red[3]));
  __syncthreads();
  float sum = 0.f;
  for (int o = threadIdx.x; o < NOBS; o += 256) sum += expf(row[o] - m);
  sum = wsum64(sum);
  if ((threadIdx.x & 63) == 0) red[wid] = sum;
  __syncthreads();
  if (threadIdx.x == 0)
    ws[LSE_OFF + s] = m + logf(red[0] + red[1] + red[2] + red[3]);
}

// ---------------- precompute: EprobT[obs*64 + s] = exp(E[s,obs] - lse[s]) ----
__global__ __launch_bounds__(256) void emis_fill(const float* __restrict__ E,
                                                 float* __restrict__ ws) {
  const int idx = blockIdx.x * 256 + threadIdx.x;  // = obs*64 + s
  if (idx >= NS * NOBS) return;
  const int s = idx & 63;
  const int obs = idx >> 6;
  ws[ET_OFF + idx] = expf(E[(size_t)s * NOBS + obs] - ws[LSE_OFF + s]);
}

// ---------------- forward recursion: 1 batch = 1 block = 1 wave ----------------
// Matvec: rotation folded INTO the fma via v_fmac_f32_dpp row_ror:j (no DPP
// movs). 4 asm blocks (one per row-group g), each = two 8-deep sub-chains
// interleaved at latency-matched cadence; same op order as R7 -> bitwise
// identical. Reduction: trimmed permlane butterfly (pack give-value, swap,
// lane-half select) -- correct under any permlane*_swap direction semantics,
// same addition association as R7 -> bitwise identical.

#define PIN8(i)                                                                \
  asm volatile("" : "+v"(aw[(i)]), "+v"(aw[(i) + 1]), "+v"(aw[(i) + 2]),       \
                    "+v"(aw[(i) + 3]), "+v"(aw[(i) + 4]), "+v"(aw[(i) + 5]),   \
                    "+v"(aw[(i) + 6]), "+v"(aw[(i) + 7]))
#define PIN_AW() do { PIN8(0); PIN8(8); PIN8(16); PIN8(24);                    \
                      PIN8(32); PIN8(40); PIN8(48); PIN8(56); } while (0)

// stage 64 emission rows of a chunk (x values in XS) into half HALF of ebuf
#define STAGE_CHUNK(XS, HALF) do {                                             \
    _Pragma("unroll")                                                          \
    for (int k_ = 0; k_ < 64; ++k_) {                                          \
      const int xt_ = __builtin_amdgcn_readlane((XS), k_);                     \
      const float* gp_ = ET + ((size_t)(unsigned)xt_ << 6) + lane;             \
      __builtin_amdgcn_global_load_lds(gp_, &ebuf[(((HALF) << 6) + k_) << 6],  \
                                       4, 0, 0);                               \
    } } while (0)

#define EREAD(DST, ADDR, IMM)                                                  \
  asm volatile("ds_read_b32 %0, %1 offset:" #IMM : "=v"(DST) : "v"(ADDR))

// one row-group matvec: QA = sum_{j=0..7} aw[B+j]*ror_j(SV),
//                       QB = sum_{j=8..15} aw[B+j]*ror_j(SV)
// %0=QA %1=QB %2=SV %3..%18 = aw[B..B+15]; rotation fused into fmac via DPP.
#define MVBLK(QA, QB, SV, B, HEAD)                                             \
  asm volatile(HEAD                                                            \
    "v_mul_f32 %0, %2, %3\n\t"                                                 \
    "v_mul_f32_dpp %1, %2, %11 row_ror:8 row_mask:0xf bank_mask:0xf\n\t"       \
    "v_fmac_f32_dpp %0, %2, %4 row_ror:1 row_mask:0xf bank_mask:0xf\n\t"       \
    "v_fmac_f32_dpp %1, %2, %12 row_ror:9 row_mask:0xf bank_mask:0xf\n\t"      \
    "v_fmac_f32_dpp %0, %2, %5 row_ror:2 row_mask:0xf bank_mask:0xf\n\t"       \
    "v_fmac_f32_dpp %1, %2, %13 row_ror:10 row_mask:0xf bank_mask:0xf\n\t"     \
    "v_fmac_f32_dpp %0, %2, %6 row_ror:3 row_mask:0xf bank_mask:0xf\n\t"       \
    "v_fmac_f32_dpp %1, %2, %14 row_ror:11 row_mask:0xf bank_mask:0xf\n\t"     \
    "v_fmac_f32_dpp %0, %2, %7 row_ror:4 row_mask:0xf bank_mask:0xf\n\t"       \
    "v_fmac_f32_dpp %1, %2, %15 row_ror:12 row_mask:0xf bank_mask:0xf\n\t"     \
    "v_fmac_f32_dpp %0, %2, %8 row_ror:5 row_mask:0xf bank_mask:0xf\n\t"       \
    "v_fmac_f32_dpp %1, %2, %16 row_ror:13 row_mask:0xf bank_mask:0xf\n\t"     \
    "v_fmac_f32_dpp %0, %2, %9 row_ror:6 row_mask:0xf bank_mask:0xf\n\t"       \
    "v_fmac_f32_dpp %1, %2, %17 row_ror:14 row_mask:0xf bank_mask:0xf\n\t"     \
    "v_fmac_f32_dpp %0, %2, %10 row_ror:7 row_mask:0xf bank_mask:0xf\n\t"      \
    "v_fmac_f32_dpp %1, %2, %18 row_ror:15 row_mask:0xf bank_mask:0xf"         \
    : "=&v"(QA), "=&v"(QB)                                                     \
    : "v"(SV),                                                                 \
      "v"(aw[(B) + 0]), "v"(aw[(B) + 1]), "v"(aw[(B) + 2]), "v"(aw[(B) + 3]),  \
      "v"(aw[(B) + 4]), "v"(aw[(B) + 5]), "v"(aw[(B) + 6]), "v"(aw[(B) + 7]),  \
      "v"(aw[(B) + 8]), "v"(aw[(B) + 9]), "v"(aw[(B) + 10]), "v"(aw[(B) + 11]),\
      "v"(aw[(B) + 12]), "v"(aw[(B) + 13]), "v"(aw[(B) + 14]), "v"(aw[(B) + 15]))

#define STEP(u, EC) do {                                                       \
    const int t_ = t0 + (u);                                                   \
    const float e_ = EC[(u)];                                                  \
    float es_;                                                                 \
    if (((u) & 1) != 0) { /* exact pow-2 rescale every 2 steps */              \
      const unsigned srf_ = __builtin_amdgcn_readfirstlane(__float_as_uint(s));\
      const int se_ = (int)((srf_ >> 23) & 0xFFu) - 127;                       \
      es_ = e_ * __uint_as_float((unsigned)(127 - se_) << 23);                 \
      E2 += se_;                                                               \
    } else { es_ = e_; }                                                       \
    float qa0_, qb0_, qa1_, qb1_, qa2_, qb2_, qa3_, qb3_;                      \
    MVBLK(qa0_, qb0_, s, 0,  "s_nop 1\n\t");                                   \
    MVBLK(qa1_, qb1_, s, 16, "");                                              \
    MVBLK(qa2_, qb2_, s, 32, "");                                              \
    MVBLK(qa3_, qb3_, s, 48, "");                                              \
    const float q0_ = qa0_ + qb0_;                                             \
    const float q1_ = qa1_ + qb1_;                                             \
    const float q2_ = qa2_ + qb2_;                                             \
    const float q3_ = qa3_ + qb3_;                                             \
    /* stage1 (xor32): keep pair {q[2c1],q[2c1+1]}, fetch partner's partials */\
    float em_ = c1m ? q0_ : q2_;   /* give slot A = q[2*(1-c1)]   */           \
    float en_ = c1m ? q1_ : q3_;   /* give slot B = q[2*(1-c1)+1] */           \
    float emc_, enc_;                                                          \
    asm("v_mov_b32 %0, %1" : "=v"(emc_) : "v"(em_));                           \
    asm("v_mov_b32 %0, %1" : "=v"(enc_) : "v"(en_));                           \
    asm("v_permlane32_swap_b32 %0, %1" : "+v"(em_), "+v"(emc_));               \
    asm("v_permlane32_swap_b32 %0, %1" : "+v"(en_), "+v"(enc_));               \
    const float pm_ = lo32 ? em_ : emc_;   /* partner's give A */              \
    const float pn_ = lo32 ? en_ : enc_;   /* partner's give B */              \
    const float ka_ = c1m ? q2_ : q0_;     /* keep A = q[2c1]   */             \
    const float kb_ = c1m ? q3_ : q1_;     /* keep B = q[2c1+1] */             \
    const float ua_ = ka_ + pm_;                                               \
    const float ub_ = kb_ + pn_;                                               \
    /* stage2 (xor16): final g = cgrp */                                       \
    float gv_ = c0m ? ua_ : ub_;           /* give = u[other slot] */          \
    float gvc_;                                                                \
    asm("v_mov_b32 %0, %1" : "=v"(gvc_) : "v"(gv_));                           \
    asm("v_permlane16_swap_b32 %0, %1" : "+v"(gv_), "+v"(gvc_));               \
    const float pg_ = lo16 ? gv_ : gvc_;                                       \
    const float kp_ = c0m ? ub_ : ua_;                                         \
    const float fin_ = kp_ + pg_;                                              \
    const float w_ = es_ * ((t_ == 0) ? pip : fin_);                           \
    if (t_ == Tn - 1) { vs = w_; e2s = E2; }                                   \
    s = w_;                                                                    \
  } while (0)

// one 4-step group: issue next group's 4 e-reads, exact-wait current's, run 4
#define GROUP(T0, ECUR, ENXT) do {                                             \
    const int t0 = (T0);                                                       \
    { const unsigned ea_ =                                                     \
          ebase + ((unsigned)(((t0 + 4) & 127)) << 8) + ((unsigned)lane << 2); \
      EREAD(ENXT[0], ea_, 0);   EREAD(ENXT[1], ea_, 256);                      \
      EREAD(ENXT[2], ea_, 512); EREAD(ENXT[3], ea_, 768); }                    \
    asm volatile("s_waitcnt lgkmcnt(4)");                                      \
    __builtin_amdgcn_sched_barrier(0);                                         \
    STEP(0, ECUR); STEP(1, ECUR); STEP(2, ECUR); STEP(3, ECUR);                \
  } while (0)

__global__ void __attribute__((amdgpu_flat_work_group_size(64, 64)))
__attribute__((amdgpu_waves_per_eu(1, 1)))
hmm_fwd(const int* __restrict__ x, const int* __restrict__ T,
        const float* __restrict__ ws, float* __restrict__ out) {
  const int lane = threadIdx.x;
  const int b = blockIdx.x;
  const int cgrp = lane >> 4;
  const bool c0m = (cgrp & 1) != 0;
  const bool c1m = (cgrp & 2) != 0;
  const bool lo32 = lane < 32;
  const bool lo16 = (lane & 16) == 0;
  const float* __restrict__ ET = ws + ET_OFF;
  const int* __restrict__ xb = x + (size_t)b * TMAX;
  const int Tn = T[b];

  __shared__ __align__(16) float ebuf[128 * 64];  // 32 KB, 2 chunk halves
  const unsigned ebase = (unsigned)(size_t)ebuf;  // flat->LDS trunc

  // swizzled A tile for this lane: aw[g*16+j], pinned resident in VGPRs
  float aw[NS];
  {
    const float4* ar = (const float4*)(ws + ASW_OFF + lane * NS);
#pragma unroll
    for (int q = 0; q < 16; ++q) {
      float4 f = ar[q];
      aw[4 * q + 0] = f.x; aw[4 * q + 1] = f.y;
      aw[4 * q + 2] = f.z; aw[4 * q + 3] = f.w;
    }
  }
  PIN_AW();

  const float pip = ws[PIP_OFF + lane];

  // stage chunk 0, drain, prime group-0 e-reads
  int xcur = xb[lane];
  STAGE_CHUNK(xcur, 0);
  int xnext = xb[64 + lane];
  asm volatile("s_waitcnt vmcnt(0)" ::: "memory");

  float eA[4], eB[4];
  {
    const unsigned ea_ = ebase + ((unsigned)lane << 2);
    EREAD(eA[0], ea_, 0);   EREAD(eA[1], ea_, 256);
    EREAD(eA[2], ea_, 512); EREAD(eA[3], ea_, 768);
  }

  float s = 1.0f;   // exponent 0 -> se=0 at t=0
  float vs = 0.f;
  int E2 = 0, e2s = 0;

  const int nch = (Tn + 63) >> 6;
  for (int c = 0; c < nch; ++c) {
    const int tb = c << 6;
    if (c + 1 < TMAX / 64) STAGE_CHUNK(xnext, (c + 1) & 1);
    xnext = ((c + 2) < TMAX / 64) ? xb[((c + 2) << 6) + lane] : 0;
#pragma unroll 1
    for (int gp = 0; gp < 7; ++gp) {    // groups 0..13
      GROUP(tb + (gp << 3), eA, eB);
      GROUP(tb + (gp << 3) + 4, eB, eA);
    }
    GROUP(tb + 56, eA, eB);             // group 14
    // drain staging of chunk c+1 before group 15 issues next-chunk reads
    asm volatile("s_waitcnt vmcnt(0)" ::: "memory");
    GROUP(tb + 60, eB, eA);             // group 15 (loads eA for next chunk)
  }

  const float sf = wsum64(vs);
  if (lane == 0) {
    const double lp = (double)logf(sf) + (double)e2s * 0.6931471805599453;
    out[b] = (float)lp;
  }
}

extern "C" void kernel_launch(void* const* d_in, const int* in_sizes, int n_in,
                              void* d_out, int out_size, void* d_ws, size_t ws_size,
                              hipStream_t stream) {
  const int*   x  = (const int*)d_in[0];
  const int*   T  = (const int*)d_in[1];
  const float* pi = (const float*)d_in[2];
  const float* A  = (const float*)d_in[3];
  const float* E  = (const float*)d_in[4];
  float* out = (float*)d_out;
  float* ws  = (float*)d_ws;

  prep_small<<<1, 64, 0, stream>>>(pi, A, ws);
  emis_lse<<<NS, 256, 0, stream>>>(E, ws);
  emis_fill<<<(NS * NOBS + 255) / 256, 256, 0, stream>>>(E, ws);
  hmm_fwd<<<NB, 64, 0, stream>>>(x, T, ws, out);
}